// Round 10
// baseline (244.413 us; speedup 1.0000x reference)
//
#include <hip/hip_runtime.h>
#include <math.h>

#define HW1 (1024 * 1024)
#define WID 1024
#define HEI 1024

// ws layout (floats): acc[64] | pool[24*65536] | cosbuf[3*HW1]
#define POOL_OFF   64
#define POOL_FLTS  (24 * 65536)
#define COS_OFF    (POOL_OFF + POOL_FLTS)

typedef float f32x4 __attribute__((ext_vector_type(4)));

// Block-level reduce (wave shfl + LDS) then one atomicAdd per block.
__device__ __forceinline__ void block_atomic_add(float v, float* target, volatile float* sdata) {
#pragma unroll
    for (int off = 32; off > 0; off >>= 1)
        v += __shfl_down(v, off, 64);
    const int lane = threadIdx.x & 63;
    const int wv   = threadIdx.x >> 6;
    if (lane == 0) sdata[wv] = v;
    __syncthreads();
    if (threadIdx.x == 0) {
        float s = 0.f;
        for (int i = 0; i < 4; ++i) s += sdata[i];
        atomicAdd(target, s);
    }
    __syncthreads();
}

// Kernel A — byte-identical gather loop to round 5 (measured 93 us).
// Blocks [0,1536): main, one (pool-row gy, channel c, half-row h) each.
// Blocks [1536,2304): Sobel s_loss on batch-0 planes.
// cos components: NON-atomic stores to cosbuf[c][pixel] (every element
// written exactly once per call -> no memset, no atomics).
__global__ __launch_bounds__(256) void k_A(const float* __restrict__ A,
                                           const float* __restrict__ B,
                                           float* __restrict__ ws) {
    __shared__ float pdl[8 * 4 * 128];   // [b][yl][cell], cell = k*64+xl
    __shared__ float s1[4];

    float* acc    = ws;
    float* pool   = ws + POOL_OFF;
    float* cosbuf = ws + COS_OFF;

    const int tid = threadIdx.x;

    if (blockIdx.x < 1536) {
        const int m  = blockIdx.x;
        const int gy = m / 6;            // pool-y 0..255
        const int r6 = m % 6;
        const int c  = r6 >> 1;          // channel 0..2
        const int h  = r6 & 1;           // half-row 0..1
        const int xl = tid & 63;
        const int yl = tid >> 6;         // row within pool cell
        const int y  = gy * 4 + yl;

        const f32x4* A4 = reinterpret_cast<const f32x4*>(A);
        const f32x4* B4 = reinterpret_cast<const f32x4*>(B);
        f32x4* C4 = reinterpret_cast<f32x4*>(cosbuf);
        // float4 base index of this row's half: row y, columns [h*512, h*512+512)
        const int rbase = y * 256 + h * 128;

        float na2[8], nb2[8], dt[8];     // 8 pixels: k in {0,1} x 4 lanes of float4
#pragma unroll
        for (int i = 0; i < 8; ++i) { na2[i] = 0.f; nb2[i] = 0.f; dt[i] = 0.f; }
        float r_sum = 0.f;

#pragma unroll
        for (int b = 0; b < 8; ++b) {
            const int pbase = (b * 3 + c) * (HW1 / 4) + rbase;
            // 4 loads: two consecutive 1KB chunks of A, same of B (linear bursts)
            const f32x4 a0 = A4[pbase + xl];
            const f32x4 a1 = A4[pbase + 64 + xl];
            const f32x4 b0 = B4[pbase + xl];
            const f32x4 b1 = B4[pbase + 64 + xl];

            float pd0 = 0.f, pd1 = 0.f;
#pragma unroll
            for (int j = 0; j < 4; ++j) {
                const float a = a0[j], t = b0[j];
                na2[j] += a * a; nb2[j] += t * t; dt[j] += a * t;
                r_sum += fabsf(a - t); pd0 += t - a;
            }
#pragma unroll
            for (int j = 0; j < 4; ++j) {
                const float a = a1[j], t = b1[j];
                na2[4 + j] += a * a; nb2[4 + j] += t * t; dt[4 + j] += a * t;
                r_sum += fabsf(a - t); pd1 += t - a;
            }
            pdl[(b * 4 + yl) * 128 + xl]      = pd0;
            pdl[(b * 4 + yl) * 128 + 64 + xl] = pd1;
        }

        // per-pixel channel cos component -> plain coalesced float4 store
#pragma unroll
        for (int k = 0; k < 2; ++k) {
            f32x4 fv;
#pragma unroll
            for (int j = 0; j < 4; ++j) {
                const int i  = k * 4 + j;
                const float na = fmaxf(sqrtf(na2[i]), 1e-12f);
                const float nb = fmaxf(sqrtf(nb2[i]), 1e-12f);
                fv[j] = dt[i] / (na * nb);
            }
            C4[c * (HW1 / 4) + rbase + k * 64 + xl] = fv;
        }

        __syncthreads();
        // pool reduce: 8 b x 128 cells, 4 per thread
#pragma unroll
        for (int i = 0; i < 4; ++i) {
            const int s    = i * 256 + tid;
            const int b    = s >> 7;
            const int cell = s & 127;
            const float v = pdl[(b * 4 + 0) * 128 + cell] + pdl[(b * 4 + 1) * 128 + cell]
                          + pdl[(b * 4 + 2) * 128 + cell] + pdl[(b * 4 + 3) * 128 + cell];
            pool[(size_t)(b * 3 + c) * 65536 + gy * 256 + h * 128 + cell] = v * (1.0f / 16.0f);
        }

        block_atomic_add(r_sum, acc + 0, s1);
    } else {
        // ---------------- Sobel path: 4x4 output tile per thread ----------------
        const int t   = (blockIdx.x - 1536) * 256 + tid;  // 0 .. 196607
        const int qx  = t & 255;
        const int rem = t >> 8;
        const int qy  = rem & 255;
        const int c   = rem >> 8;
        const int x0  = qx * 4;
        const int y0  = qy * 4;

        const float* Ap = A + (size_t)c * HW1;
        const float* Bp = B + (size_t)c * HW1;

        float rd[6][4];  // rowdiff(y,x) = d(y,x-1) - d(y,x+1), rows y0-1..y0+4
#pragma unroll
        for (int r = 0; r < 6; ++r) {
            const int yy = y0 - 1 + r;
            if (yy < 0 || yy >= HEI) {
                rd[r][0] = rd[r][1] = rd[r][2] = rd[r][3] = 0.f;
                continue;
            }
            const float* ap = Ap + (size_t)yy * WID;
            const float* bp = Bp + (size_t)yy * WID;
            const float4 a4 = *reinterpret_cast<const float4*>(ap + x0);
            const float4 b4 = *reinterpret_cast<const float4*>(bp + x0);
            const float dm = (qx > 0)   ? (ap[x0 - 1] - bp[x0 - 1]) : 0.f;
            const float dp = (qx < 255) ? (ap[x0 + 4] - bp[x0 + 4]) : 0.f;
            const float d0 = a4.x - b4.x;
            const float d1 = a4.y - b4.y;
            const float d2 = a4.z - b4.z;
            const float d3 = a4.w - b4.w;
            rd[r][0] = dm - d1;
            rd[r][1] = d0 - d2;
            rd[r][2] = d1 - d3;
            rd[r][3] = d2 - dp;
        }

        float s = 0.f;
#pragma unroll
        for (int o = 0; o < 4; ++o)
#pragma unroll
            for (int i = 0; i < 4; ++i)
                s += fabsf(rd[o][i] + 2.f * rd[o + 1][i] + rd[o + 2][i]);

        block_atomic_add(s, acc + 2, s1);
    }
}

// Kernel B. Blocks [0,1024): cos finalize (3-plane sum + clip + acos + reduce).
// Blocks [1024,3072): spatial-consistency loss from pool.
// Last block combines acc[] -> out[0] (completion counter at acc[8]).
#define NB_B 3072
__global__ __launch_bounds__(256) void k_B(float* __restrict__ ws,
                                           float* __restrict__ out) {
    __shared__ float sd[4];
    float* acc    = ws;
    float* pool   = ws + POOL_OFF;
    float* cosbuf = ws + COS_OFF;

    const int tid = threadIdx.x;

    if (blockIdx.x < 1024) {
        const int i = blockIdx.x * 256 + tid;   // float4 index 0 .. 262143
        const f32x4* C4 = reinterpret_cast<const f32x4*>(cosbuf);
        const f32x4 c0 = C4[i];
        const f32x4 c1 = C4[(HW1 / 4) + i];
        const f32x4 c2 = C4[2 * (HW1 / 4) + i];
        float c_sum = 0.f;
        const float lo = -1.0f + 1e-7f, hi = 1.0f - 1e-7f;
#pragma unroll
        for (int j = 0; j < 4; ++j) {
            const float cs = c0[j] + c1[j] + c2[j];
            c_sum += acosf(fminf(fmaxf(cs, lo), hi));
        }
        block_atomic_add(c_sum, acc + 1, sd);
    } else {
        const int t = (blockIdx.x - 1024) * 256 + tid;  // 0 .. 524287
        const int x = t & 255;
        const int y = (t >> 8) & 255;
        const int b = t >> 16;

        const float* Rr = pool + (size_t)(b * 3 + 0) * 65536 + y * 256;
        const float* Gg = pool + (size_t)(b * 3 + 1) * 65536 + y * 256;
        const float* Bb = pool + (size_t)(b * 3 + 2) * 65536 + y * 256;

        const float g  = Gg[x];
        const float gl = (x > 0)   ? Gg[x - 1] : 0.f;
        const float gr = (x < 255) ? Gg[x + 1] : 0.f;
        const float d0 = g - gl;
        const float d1 = g - gr;
        const float d2 = g - Rr[x];
        const float d3 = g - Bb[x];
        const float s  = d0 * d0 + d1 * d1 + d2 * d2 + d3 * d3;

        block_atomic_add(s, acc + 3, sd);
    }

    // ---------------- completion: last block combines ----------------
    __shared__ unsigned done_rank;
    __threadfence();
    if (tid == 0)
        done_rank = atomicAdd(reinterpret_cast<unsigned*>(acc + 8), 1u);
    __syncthreads();
    if (done_rank == NB_B - 1 && tid == 0) {
        __threadfence();
        const float r = acc[0] * (1.0f / 25165824.0f);  // mean over 8*3*1024*1024
        const float c = acc[1];
        const float s = acc[2];
        const float p = acc[3] * (1.0f / 524288.0f);    // mean over 8*256*256
        out[0] = 0.5f * c + 1.0f * r + 1.0f * p + 0.1f * s;
    }
}

extern "C" void kernel_launch(void* const* d_in, const int* in_sizes, int n_in,
                              void* d_out, int out_size, void* d_ws, size_t ws_size,
                              hipStream_t stream) {
    const float* A = (const float*)d_in[0];  // predictions
    const float* B = (const float*)d_in[1];  // targets
    float* ws = (float*)d_ws;

    hipMemsetAsync(ws, 0, 64 * sizeof(float), stream);   // acc + counter only

    hipLaunchKernelGGL(k_A, dim3(2304), dim3(256), 0, stream, A, B, ws);
    hipLaunchKernelGGL(k_B, dim3(NB_B), dim3(256), 0, stream, ws, (float*)d_out);
}

// Round 11
// 100.521 us; speedup vs baseline: 2.4315x; 2.4315x over previous
//
#include <hip/hip_runtime.h>
#include <math.h>

#define HW1 (1024 * 1024)
#define WID 1024
#define HEI 1024

// ws layout (floats): acc[64] | pool[24*65536] | cosbuf[3*HW1]
#define POOL_OFF   64
#define POOL_FLTS  (24 * 65536)
#define COS_OFF    (POOL_OFF + POOL_FLTS)

typedef float f32x4 __attribute__((ext_vector_type(4)));

// Block-level reduce (wave shfl + LDS) then one atomicAdd per block.
__device__ __forceinline__ void block_atomic_add(float v, float* target, volatile float* sdata) {
#pragma unroll
    for (int off = 32; off > 0; off >>= 1)
        v += __shfl_down(v, off, 64);
    const int lane = threadIdx.x & 63;
    const int wv   = threadIdx.x >> 6;
    if (lane == 0) sdata[wv] = v;
    __syncthreads();
    if (threadIdx.x == 0) {
        float s = 0.f;
        for (int i = 0; i < 4; ++i) s += sdata[i];
        atomicAdd(target, s);
    }
    __syncthreads();
}

// Kernel A — unchanged from round 10 (measured ~49 us).
// Blocks [0,1536): main, one (pool-row gy, channel c, half-row h) each.
// Blocks [1536,2304): Sobel s_loss on batch-0 planes.
// cos components: non-atomic float4 stores (atomics here cost ~45 us — r10).
__global__ __launch_bounds__(256) void k_A(const float* __restrict__ A,
                                           const float* __restrict__ B,
                                           float* __restrict__ ws) {
    __shared__ float pdl[8 * 4 * 128];   // [b][yl][cell], cell = k*64+xl
    __shared__ float s1[4];

    float* acc    = ws;
    float* pool   = ws + POOL_OFF;
    float* cosbuf = ws + COS_OFF;

    const int tid = threadIdx.x;

    if (blockIdx.x < 1536) {
        const int m  = blockIdx.x;
        const int gy = m / 6;            // pool-y 0..255
        const int r6 = m % 6;
        const int c  = r6 >> 1;          // channel 0..2
        const int h  = r6 & 1;           // half-row 0..1
        const int xl = tid & 63;
        const int yl = tid >> 6;         // row within pool cell
        const int y  = gy * 4 + yl;

        const f32x4* A4 = reinterpret_cast<const f32x4*>(A);
        const f32x4* B4 = reinterpret_cast<const f32x4*>(B);
        f32x4* C4 = reinterpret_cast<f32x4*>(cosbuf);
        // float4 base index of this row's half: row y, columns [h*512, h*512+512)
        const int rbase = y * 256 + h * 128;

        float na2[8], nb2[8], dt[8];     // 8 pixels: k in {0,1} x 4 lanes of float4
#pragma unroll
        for (int i = 0; i < 8; ++i) { na2[i] = 0.f; nb2[i] = 0.f; dt[i] = 0.f; }
        float r_sum = 0.f;

#pragma unroll
        for (int b = 0; b < 8; ++b) {
            const int pbase = (b * 3 + c) * (HW1 / 4) + rbase;
            // 4 loads: two consecutive 1KB chunks of A, same of B (linear bursts)
            const f32x4 a0 = A4[pbase + xl];
            const f32x4 a1 = A4[pbase + 64 + xl];
            const f32x4 b0 = B4[pbase + xl];
            const f32x4 b1 = B4[pbase + 64 + xl];

            float pd0 = 0.f, pd1 = 0.f;
#pragma unroll
            for (int j = 0; j < 4; ++j) {
                const float a = a0[j], t = b0[j];
                na2[j] += a * a; nb2[j] += t * t; dt[j] += a * t;
                r_sum += fabsf(a - t); pd0 += t - a;
            }
#pragma unroll
            for (int j = 0; j < 4; ++j) {
                const float a = a1[j], t = b1[j];
                na2[4 + j] += a * a; nb2[4 + j] += t * t; dt[4 + j] += a * t;
                r_sum += fabsf(a - t); pd1 += t - a;
            }
            pdl[(b * 4 + yl) * 128 + xl]      = pd0;
            pdl[(b * 4 + yl) * 128 + 64 + xl] = pd1;
        }

        // per-pixel channel cos component -> plain coalesced float4 store
#pragma unroll
        for (int k = 0; k < 2; ++k) {
            f32x4 fv;
#pragma unroll
            for (int j = 0; j < 4; ++j) {
                const int i  = k * 4 + j;
                const float na = fmaxf(sqrtf(na2[i]), 1e-12f);
                const float nb = fmaxf(sqrtf(nb2[i]), 1e-12f);
                fv[j] = dt[i] / (na * nb);
            }
            C4[c * (HW1 / 4) + rbase + k * 64 + xl] = fv;
        }

        __syncthreads();
        // pool reduce: 8 b x 128 cells, 4 per thread
#pragma unroll
        for (int i = 0; i < 4; ++i) {
            const int s    = i * 256 + tid;
            const int b    = s >> 7;
            const int cell = s & 127;
            const float v = pdl[(b * 4 + 0) * 128 + cell] + pdl[(b * 4 + 1) * 128 + cell]
                          + pdl[(b * 4 + 2) * 128 + cell] + pdl[(b * 4 + 3) * 128 + cell];
            pool[(size_t)(b * 3 + c) * 65536 + gy * 256 + h * 128 + cell] = v * (1.0f / 16.0f);
        }

        block_atomic_add(r_sum, acc + 0, s1);
    } else {
        // ---------------- Sobel path: 4x4 output tile per thread ----------------
        const int t   = (blockIdx.x - 1536) * 256 + tid;  // 0 .. 196607
        const int qx  = t & 255;
        const int rem = t >> 8;
        const int qy  = rem & 255;
        const int c   = rem >> 8;
        const int x0  = qx * 4;
        const int y0  = qy * 4;

        const float* Ap = A + (size_t)c * HW1;
        const float* Bp = B + (size_t)c * HW1;

        float rd[6][4];  // rowdiff(y,x) = d(y,x-1) - d(y,x+1), rows y0-1..y0+4
#pragma unroll
        for (int r = 0; r < 6; ++r) {
            const int yy = y0 - 1 + r;
            if (yy < 0 || yy >= HEI) {
                rd[r][0] = rd[r][1] = rd[r][2] = rd[r][3] = 0.f;
                continue;
            }
            const float* ap = Ap + (size_t)yy * WID;
            const float* bp = Bp + (size_t)yy * WID;
            const float4 a4 = *reinterpret_cast<const float4*>(ap + x0);
            const float4 b4 = *reinterpret_cast<const float4*>(bp + x0);
            const float dm = (qx > 0)   ? (ap[x0 - 1] - bp[x0 - 1]) : 0.f;
            const float dp = (qx < 255) ? (ap[x0 + 4] - bp[x0 + 4]) : 0.f;
            const float d0 = a4.x - b4.x;
            const float d1 = a4.y - b4.y;
            const float d2 = a4.z - b4.z;
            const float d3 = a4.w - b4.w;
            rd[r][0] = dm - d1;
            rd[r][1] = d0 - d2;
            rd[r][2] = d1 - d3;
            rd[r][3] = d2 - dp;
        }

        float s = 0.f;
#pragma unroll
        for (int o = 0; o < 4; ++o)
#pragma unroll
            for (int i = 0; i < 4; ++i)
                s += fabsf(rd[o][i] + 2.f * rd[o + 1][i] + rd[o + 2][i]);

        block_atomic_add(s, acc + 2, s1);
    }
}

// Kernel B. Blocks [0,1024): cos finalize (3-plane sum + clip + acos + reduce).
// Blocks [1024,3072): spatial-consistency loss from pool.
// NO completion counter / NO __threadfence: per-block agent fences cost ~0.5us
// of serialized L2 writeback each (r10: 3072 fences -> 195us). k_final is a
// separate launch; the kernel boundary provides ordering+visibility.
__global__ __launch_bounds__(256) void k_B(float* __restrict__ ws) {
    __shared__ float sd[4];
    float* acc    = ws;
    float* pool   = ws + POOL_OFF;
    float* cosbuf = ws + COS_OFF;

    const int tid = threadIdx.x;

    if (blockIdx.x < 1024) {
        const int i = blockIdx.x * 256 + tid;   // float4 index 0 .. 262143
        const f32x4* C4 = reinterpret_cast<const f32x4*>(cosbuf);
        const f32x4 c0 = C4[i];
        const f32x4 c1 = C4[(HW1 / 4) + i];
        const f32x4 c2 = C4[2 * (HW1 / 4) + i];
        float c_sum = 0.f;
        const float lo = -1.0f + 1e-7f, hi = 1.0f - 1e-7f;
#pragma unroll
        for (int j = 0; j < 4; ++j) {
            const float cs = c0[j] + c1[j] + c2[j];
            c_sum += acosf(fminf(fmaxf(cs, lo), hi));
        }
        block_atomic_add(c_sum, acc + 1, sd);
    } else {
        const int t = (blockIdx.x - 1024) * 256 + tid;  // 0 .. 524287
        const int x = t & 255;
        const int y = (t >> 8) & 255;
        const int b = t >> 16;

        const float* Rr = pool + (size_t)(b * 3 + 0) * 65536 + y * 256;
        const float* Gg = pool + (size_t)(b * 3 + 1) * 65536 + y * 256;
        const float* Bb = pool + (size_t)(b * 3 + 2) * 65536 + y * 256;

        const float g  = Gg[x];
        const float gl = (x > 0)   ? Gg[x - 1] : 0.f;
        const float gr = (x < 255) ? Gg[x + 1] : 0.f;
        const float d0 = g - gl;
        const float d1 = g - gr;
        const float d2 = g - Rr[x];
        const float d3 = g - Bb[x];
        const float s  = d0 * d0 + d1 * d1 + d2 * d2 + d3 * d3;

        block_atomic_add(s, acc + 3, sd);
    }
}

// Combine: out = W_C*c + W_R*r + W_P*p + W_S*s
__global__ void k_final(const float* __restrict__ acc, float* __restrict__ out) {
    const float r = acc[0] * (1.0f / 25165824.0f);  // mean over 8*3*1024*1024
    const float c = acc[1];
    const float s = acc[2];
    const float p = acc[3] * (1.0f / 524288.0f);    // mean over 8*256*256
    out[0] = 0.5f * c + 1.0f * r + 1.0f * p + 0.1f * s;
}

extern "C" void kernel_launch(void* const* d_in, const int* in_sizes, int n_in,
                              void* d_out, int out_size, void* d_ws, size_t ws_size,
                              hipStream_t stream) {
    const float* A = (const float*)d_in[0];  // predictions
    const float* B = (const float*)d_in[1];  // targets
    float* ws = (float*)d_ws;

    hipMemsetAsync(ws, 0, 64 * sizeof(float), stream);   // acc only

    hipLaunchKernelGGL(k_A,     dim3(2304), dim3(256), 0, stream, A, B, ws);
    hipLaunchKernelGGL(k_B,     dim3(3072), dim3(256), 0, stream, ws);
    hipLaunchKernelGGL(k_final, dim3(1),    dim3(1),   0, stream, ws, (float*)d_out);
}

// Round 12
// 98.542 us; speedup vs baseline: 2.4803x; 1.0201x over previous
//
#include <hip/hip_runtime.h>
#include <math.h>

#define HW1 (1024 * 1024)
#define WID 1024
#define HEI 1024

// ws layout (floats): acc[64] | pool[24*65536] | cosbuf[3*HW1]
#define POOL_OFF   64
#define POOL_FLTS  (24 * 65536)
#define COS_OFF    (POOL_OFF + POOL_FLTS)

typedef float f32x4 __attribute__((ext_vector_type(4)));

// Block-level reduce (wave shfl + LDS) then one atomicAdd per block.
__device__ __forceinline__ void block_atomic_add(float v, float* target, volatile float* sdata) {
#pragma unroll
    for (int off = 32; off > 0; off >>= 1)
        v += __shfl_down(v, off, 64);
    const int lane = threadIdx.x & 63;
    const int wv   = threadIdx.x >> 6;
    if (lane == 0) sdata[wv] = v;
    __syncthreads();
    if (threadIdx.x == 0) {
        float s = 0.f;
        for (int i = 0; i < 4; ++i) s += sdata[i];
        atomicAdd(target, s);
    }
    __syncthreads();
}

// Kernel A, 4KB-run variant.
// Blocks [0,768): main, block=(gy,c): full pool row, one channel.
//   Wave w owns image row 4*gy+w and sweeps it in 4 chunks: per array a
//   4KB sequential run per plane-visit (lane l -> float4 l,64+l,128+l,192+l).
//   8 loads issued back-to-back (8KB in flight/wave).
// Blocks [768,1536): Sobel s_loss on batch-0 planes (unchanged).
__global__ __launch_bounds__(256) void k_A(const float* __restrict__ A,
                                           const float* __restrict__ B,
                                           float* __restrict__ ws) {
    __shared__ float pdl[8 * 4 * 256];   // [b][wave(row)][cell] raw pd sums; 32 KB
    __shared__ float s1[4];

    float* acc    = ws;
    float* pool   = ws + POOL_OFF;
    float* cosbuf = ws + COS_OFF;

    const int tid = threadIdx.x;

    if (blockIdx.x < 768) {
        const int gy = blockIdx.x >> 2;        // pool-y 0..255  (gy = blk/4... careful)
        // NOTE: 768 = 256 gy * 3 c. Decode as gy-major for dispatch spread:
        const int m  = blockIdx.x;
        const int gy2 = m / 3;                 // pool-y 0..255
        const int c   = m % 3;                 // channel
        (void)gy;
        const int l  = tid & 63;               // lane
        const int w  = tid >> 6;               // wave = row within pool row
        const int y  = gy2 * 4 + w;
        const int rbase = y * 256;             // float4 index of row start in plane

        const f32x4* A4 = reinterpret_cast<const f32x4*>(A);
        const f32x4* B4 = reinterpret_cast<const f32x4*>(B);
        f32x4* C4 = reinterpret_cast<f32x4*>(cosbuf);

        float na2[4][4], nb2[4][4], dt[4][4];  // [chunk][j] — all static indexing
#pragma unroll
        for (int k = 0; k < 4; ++k)
#pragma unroll
            for (int j = 0; j < 4; ++j) { na2[k][j] = 0.f; nb2[k][j] = 0.f; dt[k][j] = 0.f; }
        float r_sum = 0.f;

#pragma unroll 2
        for (int b = 0; b < 8; ++b) {
            const int pbase = (b * 3 + c) * (HW1 / 4) + rbase;
            f32x4 av[4], bv[4];
            // issue all 8 loads back-to-back: two 4KB sequential runs per wave
#pragma unroll
            for (int k = 0; k < 4; ++k) av[k] = A4[pbase + k * 64 + l];
#pragma unroll
            for (int k = 0; k < 4; ++k) bv[k] = B4[pbase + k * 64 + l];
#pragma unroll
            for (int k = 0; k < 4; ++k) {
                float pd = 0.f;
#pragma unroll
                for (int j = 0; j < 4; ++j) {
                    const float a = av[k][j], t = bv[k][j];
                    na2[k][j] += a * a; nb2[k][j] += t * t; dt[k][j] += a * t;
                    r_sum += fabsf(a - t); pd += t - a;
                }
                pdl[(b * 4 + w) * 256 + k * 64 + l] = pd;
            }
        }

        // cos components for this thread's 16 pixels -> coalesced float4 stores
#pragma unroll
        for (int k = 0; k < 4; ++k) {
            f32x4 fv;
#pragma unroll
            for (int j = 0; j < 4; ++j) {
                const float na = fmaxf(sqrtf(na2[k][j]), 1e-12f);
                const float nb = fmaxf(sqrtf(nb2[k][j]), 1e-12f);
                fv[j] = dt[k][j] / (na * nb);
            }
            C4[c * (HW1 / 4) + rbase + k * 64 + l] = fv;
        }

        __syncthreads();
        // pool reduce: 8 b x 256 cells = 2048 values, 8 per thread
#pragma unroll
        for (int i = 0; i < 8; ++i) {
            const int s    = i * 256 + tid;
            const int b    = s >> 8;
            const int cell = s & 255;
            const float v = pdl[(b * 4 + 0) * 256 + cell] + pdl[(b * 4 + 1) * 256 + cell]
                          + pdl[(b * 4 + 2) * 256 + cell] + pdl[(b * 4 + 3) * 256 + cell];
            pool[(size_t)(b * 3 + c) * 65536 + gy2 * 256 + cell] = v * (1.0f / 16.0f);
        }

        block_atomic_add(r_sum, acc + 0, s1);
    } else {
        // ---------------- Sobel path: 4x4 output tile per thread ----------------
        const int t   = (blockIdx.x - 768) * 256 + tid;  // 0 .. 196607
        const int qx  = t & 255;
        const int rem = t >> 8;
        const int qy  = rem & 255;
        const int c   = rem >> 8;
        const int x0  = qx * 4;
        const int y0  = qy * 4;

        const float* Ap = A + (size_t)c * HW1;
        const float* Bp = B + (size_t)c * HW1;

        float rd[6][4];  // rowdiff(y,x) = d(y,x-1) - d(y,x+1), rows y0-1..y0+4
#pragma unroll
        for (int r = 0; r < 6; ++r) {
            const int yy = y0 - 1 + r;
            if (yy < 0 || yy >= HEI) {
                rd[r][0] = rd[r][1] = rd[r][2] = rd[r][3] = 0.f;
                continue;
            }
            const float* ap = Ap + (size_t)yy * WID;
            const float* bp = Bp + (size_t)yy * WID;
            const float4 a4 = *reinterpret_cast<const float4*>(ap + x0);
            const float4 b4 = *reinterpret_cast<const float4*>(bp + x0);
            const float dm = (qx > 0)   ? (ap[x0 - 1] - bp[x0 - 1]) : 0.f;
            const float dp = (qx < 255) ? (ap[x0 + 4] - bp[x0 + 4]) : 0.f;
            const float d0 = a4.x - b4.x;
            const float d1 = a4.y - b4.y;
            const float d2 = a4.z - b4.z;
            const float d3 = a4.w - b4.w;
            rd[r][0] = dm - d1;
            rd[r][1] = d0 - d2;
            rd[r][2] = d1 - d3;
            rd[r][3] = d2 - dp;
        }

        float s = 0.f;
#pragma unroll
        for (int o = 0; o < 4; ++o)
#pragma unroll
            for (int i = 0; i < 4; ++i)
                s += fabsf(rd[o][i] + 2.f * rd[o + 1][i] + rd[o + 2][i]);

        block_atomic_add(s, acc + 2, s1);
    }
}

// Kernel B. Blocks [0,1024): cos finalize (3-plane sum + clip + acos + reduce).
// Blocks [1024,3072): spatial-consistency loss from pool. No fences (r10 lesson).
__global__ __launch_bounds__(256) void k_B(float* __restrict__ ws) {
    __shared__ float sd[4];
    float* acc    = ws;
    float* pool   = ws + POOL_OFF;
    float* cosbuf = ws + COS_OFF;

    const int tid = threadIdx.x;

    if (blockIdx.x < 1024) {
        const int i = blockIdx.x * 256 + tid;   // float4 index 0 .. 262143
        const f32x4* C4 = reinterpret_cast<const f32x4*>(cosbuf);
        const f32x4 c0 = C4[i];
        const f32x4 c1 = C4[(HW1 / 4) + i];
        const f32x4 c2 = C4[2 * (HW1 / 4) + i];
        float c_sum = 0.f;
        const float lo = -1.0f + 1e-7f, hi = 1.0f - 1e-7f;
#pragma unroll
        for (int j = 0; j < 4; ++j) {
            const float cs = c0[j] + c1[j] + c2[j];
            c_sum += acosf(fminf(fmaxf(cs, lo), hi));
        }
        block_atomic_add(c_sum, acc + 1, sd);
    } else {
        const int t = (blockIdx.x - 1024) * 256 + tid;  // 0 .. 524287
        const int x = t & 255;
        const int y = (t >> 8) & 255;
        const int b = t >> 16;

        const float* Rr = pool + (size_t)(b * 3 + 0) * 65536 + y * 256;
        const float* Gg = pool + (size_t)(b * 3 + 1) * 65536 + y * 256;
        const float* Bb = pool + (size_t)(b * 3 + 2) * 65536 + y * 256;

        const float g  = Gg[x];
        const float gl = (x > 0)   ? Gg[x - 1] : 0.f;
        const float gr = (x < 255) ? Gg[x + 1] : 0.f;
        const float d0 = g - gl;
        const float d1 = g - gr;
        const float d2 = g - Rr[x];
        const float d3 = g - Bb[x];
        const float s  = d0 * d0 + d1 * d1 + d2 * d2 + d3 * d3;

        block_atomic_add(s, acc + 3, sd);
    }
}

// Combine: out = W_C*c + W_R*r + W_P*p + W_S*s
__global__ void k_final(const float* __restrict__ acc, float* __restrict__ out) {
    const float r = acc[0] * (1.0f / 25165824.0f);  // mean over 8*3*1024*1024
    const float c = acc[1];
    const float s = acc[2];
    const float p = acc[3] * (1.0f / 524288.0f);    // mean over 8*256*256
    out[0] = 0.5f * c + 1.0f * r + 1.0f * p + 0.1f * s;
}

extern "C" void kernel_launch(void* const* d_in, const int* in_sizes, int n_in,
                              void* d_out, int out_size, void* d_ws, size_t ws_size,
                              hipStream_t stream) {
    const float* A = (const float*)d_in[0];  // predictions
    const float* B = (const float*)d_in[1];  // targets
    float* ws = (float*)d_ws;

    hipMemsetAsync(ws, 0, 64 * sizeof(float), stream);   // acc only

    hipLaunchKernelGGL(k_A,     dim3(1536), dim3(256), 0, stream, A, B, ws);
    hipLaunchKernelGGL(k_B,     dim3(3072), dim3(256), 0, stream, ws);
    hipLaunchKernelGGL(k_final, dim3(1),    dim3(1),   0, stream, ws, (float*)d_out);
}

// Round 13
// 63.381 us; speedup vs baseline: 3.8562x; 1.5547x over previous
//
#include <hip/hip_runtime.h>
#include <math.h>

#define HW1 (1024 * 1024)
#define WID 1024
#define HEI 1024
#define NMAIN 512            // (gy 0..255) x (h 0..1)
#define NSOB  384            // sobel: 3 planes x 256 y-tiles x 128 x-tiles / 256 thr
#define NBLK  (NMAIN + NSOB)

typedef float f32x4 __attribute__((ext_vector_type(4)));

// Block-level reduce (wave shfl + LDS) then one atomicAdd per block.
__device__ __forceinline__ void block_atomic_add(float v, float* target, volatile float* sdata) {
#pragma unroll
    for (int off = 32; off > 0; off >>= 1)
        v += __shfl_down(v, off, 64);
    const int lane = threadIdx.x & 63;
    const int wv   = threadIdx.x >> 6;
    if (lane == 0) sdata[wv] = v;
    __syncthreads();
    if (threadIdx.x == 0) {
        float s = 0.f;
        for (int i = 0; i < 4; ++i) s += sdata[i];
        atomicAdd(target, s);
    }
    __syncthreads();
}

// ONE worker kernel, zero global intermediates.
// Blocks [0,512): main. Block=(gy,h): 4 image rows x 512 cols, ALL 3 channels.
//   - r_loss, c_loss thread-local (channels in-thread)
//   - pd (pooled diff) -> LDS [8][3][4][130] with ghost cols 0/129; p_loss in-block.
//   - G-channel ghost cells loaded in a small epilogue (outside the hot loop).
// Blocks [512,896): Sobel on batch-0, 4x8 output tile per thread.
__global__ __launch_bounds__(256) void k_A(const float* __restrict__ A,
                                           const float* __restrict__ B,
                                           float* __restrict__ acc) {
    __shared__ float pd[8][3][4][130];   // [b][c][yl][slot]; slot 1..128 main, 0/129 ghosts
    __shared__ float s1[4];

    const int tid = threadIdx.x;

    if (blockIdx.x < NMAIN) {
        const int gy = blockIdx.x >> 1;      // pool row 0..255
        const int h  = blockIdx.x & 1;       // half-row
        const int xl = tid & 63;
        const int yl = tid >> 6;             // image row within pool row
        const int y  = gy * 4 + yl;
        const int rbase = y * 256 + h * 128; // float4 index of this half-row

        const f32x4* A4 = reinterpret_cast<const f32x4*>(A);
        const f32x4* B4 = reinterpret_cast<const f32x4*>(B);

        float na2[3][8], nb2[3][8], dt[3][8];   // [c][pixel] — all static indexing
#pragma unroll
        for (int c = 0; c < 3; ++c)
#pragma unroll
            for (int j = 0; j < 8; ++j) { na2[c][j] = 0.f; nb2[c][j] = 0.f; dt[c][j] = 0.f; }
        float r_sum = 0.f;

#pragma unroll 2
        for (int b = 0; b < 8; ++b) {
#pragma unroll
            for (int c = 0; c < 3; ++c) {
                const int pbase = (b * 3 + c) * (HW1 / 4) + rbase;
                const f32x4 a0 = A4[pbase + xl];
                const f32x4 a1 = A4[pbase + 64 + xl];
                const f32x4 b0 = B4[pbase + xl];
                const f32x4 b1 = B4[pbase + 64 + xl];
                float pd0 = 0.f, pd1 = 0.f;
#pragma unroll
                for (int j = 0; j < 4; ++j) {
                    const float a = a0[j], t = b0[j];
                    na2[c][j] += a * a; nb2[c][j] += t * t; dt[c][j] += a * t;
                    r_sum += fabsf(a - t); pd0 += t - a;
                }
#pragma unroll
                for (int j = 0; j < 4; ++j) {
                    const float a = a1[j], t = b1[j];
                    na2[c][4 + j] += a * a; nb2[c][4 + j] += t * t; dt[c][4 + j] += a * t;
                    r_sum += fabsf(a - t); pd1 += t - a;
                }
                pd[b][c][yl][1 + xl]  = pd0;
                pd[b][c][yl][65 + xl] = pd1;
            }
        }

        // ---- ghost columns (outside hot loop, branch-free inner) ----
        // Zero all ghost slots except the G-channel data side; 32 lanes load the
        // G-channel neighbor cell (4 cols) per (b, yl).
        if (tid < 192) {
            const int side = tid & 1;            // 0 = slot 0, 1 = slot 129
            const int yl2  = (tid >> 1) & 3;
            const int c2   = (tid >> 3) % 3;
            const int b2   = tid / 24;
            const int dataside = (h == 0) ? 1 : 0;
            if (!(c2 == 1 && side == dataside))
                pd[b2][c2][yl2][side ? 129 : 0] = 0.f;
        } else if (tid < 224) {
            const int i2  = tid - 192;
            const int b2  = i2 >> 2;
            const int yl2 = i2 & 3;
            const int gcol = (h == 0) ? 128 : 127;   // neighbor pool cell's float4 col
            const int slot = (h == 0) ? 129 : 0;
            const int gp = (b2 * 3 + 1) * (HW1 / 4) + (gy * 4 + yl2) * 256 + gcol;
            const f32x4 ga = A4[gp];
            const f32x4 gb = B4[gp];
            pd[b2][1][yl2][slot] = (gb[0] - ga[0]) + (gb[1] - ga[1])
                                 + (gb[2] - ga[2]) + (gb[3] - ga[3]);
        }

        // ---- c_loss: thread-local over its 8 pixels ----
        float c_sum = 0.f;
#pragma unroll
        for (int j = 0; j < 8; ++j) {
            float cs = 0.f;
#pragma unroll
            for (int c = 0; c < 3; ++c) {
                const float na = fmaxf(sqrtf(na2[c][j]), 1e-12f);
                const float nb = fmaxf(sqrtf(nb2[c][j]), 1e-12f);
                cs += dt[c][j] / (na * nb);
            }
            cs = fminf(fmaxf(cs, -1.0f + 1e-7f), 1.0f - 1e-7f);
            c_sum += acosf(cs);
        }

        __syncthreads();

        // ---- p_loss in-block: 8 b x 128 cells = 1024 items, 4/thread ----
        // pd holds 16x pool values; fold /16^2 into one 1/256 scale.
        float p_sum = 0.f;
#pragma unroll
        for (int i = 0; i < 4; ++i) {
            const int item = i * 256 + tid;
            const int b2 = item >> 7;
            const int x  = item & 127;
            float g = 0.f, gl = 0.f, gr = 0.f, rr = 0.f, bb = 0.f;
#pragma unroll
            for (int yy = 0; yy < 4; ++yy) {
                g  += pd[b2][1][yy][1 + x];
                gl += pd[b2][1][yy][x];
                gr += pd[b2][1][yy][2 + x];
                rr += pd[b2][0][yy][1 + x];
                bb += pd[b2][2][yy][1 + x];
            }
            const float d0 = g - gl;
            const float d1 = g - gr;
            const float d2 = g - rr;
            const float d3 = g - bb;
            p_sum += d0 * d0 + d1 * d1 + d2 * d2 + d3 * d3;
        }
        p_sum *= (1.0f / 256.0f);

        block_atomic_add(r_sum, acc + 0, s1);
        block_atomic_add(c_sum, acc + 1, s1);
        block_atomic_add(p_sum, acc + 3, s1);
    } else {
        // ---------------- Sobel path: 4x8 output tile per thread ----------------
        const int t   = (blockIdx.x - NMAIN) * 256 + tid;  // 0 .. 98303
        const int xt  = t & 127;
        const int rem = t >> 7;
        const int yt  = rem & 255;
        const int c   = rem >> 8;          // 0..2
        const int x0  = xt * 8;
        const int y0  = yt * 4;

        const float* Ap = A + (size_t)c * HW1;
        const float* Bp = B + (size_t)c * HW1;

        float rd[6][8];  // rowdiff(y,x) = d(y,x-1) - d(y,x+1), rows y0-1..y0+4
#pragma unroll
        for (int r = 0; r < 6; ++r) {
            const int yy = y0 - 1 + r;
            if (yy < 0 || yy >= HEI) {
#pragma unroll
                for (int j = 0; j < 8; ++j) rd[r][j] = 0.f;
                continue;
            }
            const float* ap = Ap + (size_t)yy * WID;
            const float* bp = Bp + (size_t)yy * WID;
            const float4 a4 = *reinterpret_cast<const float4*>(ap + x0);
            const float4 a5 = *reinterpret_cast<const float4*>(ap + x0 + 4);
            const float4 b4 = *reinterpret_cast<const float4*>(bp + x0);
            const float4 b5 = *reinterpret_cast<const float4*>(bp + x0 + 4);
            const float dm = (x0 > 0)    ? (ap[x0 - 1] - bp[x0 - 1]) : 0.f;
            const float dp = (x0 < 1016) ? (ap[x0 + 8] - bp[x0 + 8]) : 0.f;
            const float d0 = a4.x - b4.x, d1 = a4.y - b4.y, d2 = a4.z - b4.z, d3 = a4.w - b4.w;
            const float d4 = a5.x - b5.x, d5 = a5.y - b5.y, d6 = a5.z - b5.z, d7 = a5.w - b5.w;
            rd[r][0] = dm - d1;
            rd[r][1] = d0 - d2;
            rd[r][2] = d1 - d3;
            rd[r][3] = d2 - d4;
            rd[r][4] = d3 - d5;
            rd[r][5] = d4 - d6;
            rd[r][6] = d5 - d7;
            rd[r][7] = d6 - dp;
        }

        float s_sum = 0.f;
#pragma unroll
        for (int o = 0; o < 4; ++o)
#pragma unroll
            for (int j = 0; j < 8; ++j)
                s_sum += fabsf(rd[o][j] + 2.f * rd[o + 1][j] + rd[o + 2][j]);

        block_atomic_add(s_sum, acc + 2, s1);
    }
}

// Combine: out = W_C*c + W_R*r + W_P*p + W_S*s
__global__ void k_final(const float* __restrict__ acc, float* __restrict__ out) {
    const float r = acc[0] * (1.0f / 25165824.0f);  // mean over 8*3*1024*1024
    const float c = acc[1];
    const float s = acc[2];
    const float p = acc[3] * (1.0f / 524288.0f);    // mean over 8*256*256
    out[0] = 0.5f * c + 1.0f * r + 1.0f * p + 0.1f * s;
}

extern "C" void kernel_launch(void* const* d_in, const int* in_sizes, int n_in,
                              void* d_out, int out_size, void* d_ws, size_t ws_size,
                              hipStream_t stream) {
    const float* A = (const float*)d_in[0];  // predictions
    const float* B = (const float*)d_in[1];  // targets
    float* acc = (float*)d_ws;               // acc[0..3]

    hipMemsetAsync(acc, 0, 64 * sizeof(float), stream);
    hipLaunchKernelGGL(k_A,     dim3(NBLK), dim3(256), 0, stream, A, B, acc);
    hipLaunchKernelGGL(k_final, dim3(1),    dim3(1),   0, stream, acc, (float*)d_out);
}